// Round 1
// baseline (894.957 us; speedup 1.0000x reference)
//
#include <hip/hip_runtime.h>
#include <math.h>
#include <float.h>

#define BGRAPH 16
#define NPTS   2048
#define CDIM   16
#define ODIM   64
#define KNN    16
#define NTOT   (BGRAPH*NPTS)     // 32768
#define NEDGE  (NTOT*KNN)        // 524288
#define EPSBN  1e-5f

// ---------------- P = x@W1b, Q = x@(W1a-W1b)+b1, sq = rowsum(x*x) ----------
__global__ __launch_bounds__(256) void pq_kernel(
    const float* __restrict__ x, const float* __restrict__ W1,
    const float* __restrict__ b1,
    float* __restrict__ P, float* __restrict__ Q, float* __restrict__ sq) {
  int lane = threadIdx.x & 63;
  int nin  = threadIdx.x >> 6;           // node within block (0..3)
  int node = blockIdx.x * 4 + nin;
  __shared__ float xs[4][CDIM];
  if (threadIdx.x < 4*CDIM) {
    int n = threadIdx.x / CDIM, c = threadIdx.x % CDIM;
    xs[n][c] = x[(blockIdx.x*4 + n)*CDIM + c];
  }
  __syncthreads();
  float p = 0.f, q = b1[lane];
  #pragma unroll
  for (int c = 0; c < CDIM; ++c) {
    float xv = xs[nin][c];
    float wb = W1[(c+CDIM)*ODIM + lane];
    float wa = W1[c*ODIM + lane];
    p += xv * wb;
    q += xv * (wa - wb);
  }
  P[node*ODIM + lane] = p;
  Q[node*ODIM + lane] = q;
  if (lane == 0) {
    float s = 0.f;
    #pragma unroll
    for (int c = 0; c < CDIM; ++c) { float xv = xs[nin][c]; s += xv*xv; }
    sq[node] = s;
  }
}

// ---------------- kNN: 4 rows per block, full 2048-col distance row in LDS --
#define ROWS 4
#define TS   256
__global__ __launch_bounds__(256) void knn_kernel(
    const float* __restrict__ x, const float* __restrict__ sq,
    int* __restrict__ idxOut) {
  __shared__ float sS[TS][CDIM+1];       // +1 pad: 17 coprime w/ 32 banks
  __shared__ float dmat[ROWS][NPTS];     // 32 KB
  __shared__ float sT[ROWS][CDIM];
  __shared__ float sqT[ROWS];
  __shared__ float redV[4];
  __shared__ int   redI[4];
  int tid = threadIdx.x;
  int blocksPerGraph = NPTS / ROWS;      // 512
  int g    = blockIdx.x / blocksPerGraph;
  int row0 = (blockIdx.x % blocksPerGraph) * ROWS;
  int gbase = g * NPTS;

  if (tid < ROWS*CDIM) {
    int r = tid / CDIM, c = tid % CDIM;
    sT[r][c] = x[(gbase + row0 + r)*CDIM + c];
  }
  if (tid < ROWS) sqT[tid] = sq[gbase + row0 + tid];

  for (int t = 0; t < NPTS/TS; ++t) {
    __syncthreads();
    const float4* srcp = (const float4*)(x + (size_t)(gbase + t*TS + tid)*CDIM);
    float4 v0 = srcp[0], v1 = srcp[1], v2 = srcp[2], v3 = srcp[3];
    sS[tid][0]=v0.x;  sS[tid][1]=v0.y;  sS[tid][2]=v0.z;  sS[tid][3]=v0.w;
    sS[tid][4]=v1.x;  sS[tid][5]=v1.y;  sS[tid][6]=v1.z;  sS[tid][7]=v1.w;
    sS[tid][8]=v2.x;  sS[tid][9]=v2.y;  sS[tid][10]=v2.z; sS[tid][11]=v2.w;
    sS[tid][12]=v3.x; sS[tid][13]=v3.y; sS[tid][14]=v3.z; sS[tid][15]=v3.w;
    __syncthreads();
    float sqs = sq[gbase + t*TS + tid];
    #pragma unroll
    for (int r = 0; r < ROWS; ++r) {
      float dot = 0.f;
      #pragma unroll
      for (int c = 0; c < CDIM; ++c) dot += sT[r][c] * sS[tid][c];
      dmat[r][t*TS + tid] = sqT[r] + sqs - 2.f*dot;
    }
  }
  __syncthreads();

  // selection: 16 argmin rounds per row
  for (int r = 0; r < ROWS; ++r) {
    for (int sel = 0; sel < KNN; ++sel) {
      float best = FLT_MAX; int bi = 0;
      #pragma unroll
      for (int s = 0; s < NPTS/256; ++s) {
        int j = tid + s*256;
        float v = dmat[r][j];
        if (v < best) { best = v; bi = j; }
      }
      #pragma unroll
      for (int off = 32; off > 0; off >>= 1) {
        float ov = __shfl_down(best, off);
        int   oi = __shfl_down(bi, off);
        if (ov < best) { best = ov; bi = oi; }
      }
      int w = tid >> 6;
      if ((tid & 63) == 0) { redV[w] = best; redI[w] = bi; }
      __syncthreads();
      if (tid == 0) {
        float bb = redV[0]; int bbi = redI[0];
        #pragma unroll
        for (int ww = 1; ww < 4; ++ww)
          if (redV[ww] < bb) { bb = redV[ww]; bbi = redI[ww]; }
        idxOut[(size_t)(gbase + row0 + r)*KNN + sel] = gbase + bbi;
        dmat[r][bbi] = FLT_MAX;
      }
      __syncthreads();
    }
  }
}

// ---------------- stats pass 1: per-channel sum/sumsq of h ------------------
__global__ __launch_bounds__(256) void stats1_kernel(
    const float* __restrict__ P, const float* __restrict__ Q,
    const int* __restrict__ idx, float* __restrict__ stats) {
  int lane = threadIdx.x & 63;
  int wid  = threadIdx.x >> 6;
  int gw   = blockIdx.x * 4 + wid;           // 0..1023
  const int npw = NTOT / 1024;               // 32 nodes per wave
  int n0 = gw * npw;
  float s = 0.f, ss = 0.f;
  for (int i = n0; i < n0 + npw; ++i) {
    float qv = Q[(size_t)i*ODIM + lane];
    #pragma unroll
    for (int k = 0; k < KNN; ++k) {
      int j = idx[(size_t)i*KNN + k];
      float h = qv + P[(size_t)j*ODIM + lane];
      s += h; ss += h*h;
    }
  }
  __shared__ float ls[ODIM], lss[ODIM];
  if (threadIdx.x < ODIM) { ls[threadIdx.x] = 0.f; lss[threadIdx.x] = 0.f; }
  __syncthreads();
  atomicAdd(&ls[lane], s);
  atomicAdd(&lss[lane], ss);
  __syncthreads();
  if (threadIdx.x < ODIM)        atomicAdd(&stats[threadIdx.x], ls[threadIdx.x]);
  else if (threadIdx.x < 2*ODIM) atomicAdd(&stats[threadIdx.x], lss[threadIdx.x - ODIM]);
}

__global__ void fin1_kernel(const float* __restrict__ stats,
    const float* __restrict__ g1, const float* __restrict__ be1,
    float* __restrict__ scale, float* __restrict__ shift) {
  int o = threadIdx.x;
  float mu  = stats[o] / (float)NEDGE;
  float var = stats[64+o] / (float)NEDGE - mu*mu;
  float inv = 1.0f / sqrtf(var + EPSBN);
  float sc = g1[o] * inv;
  scale[o] = sc;
  shift[o] = be1[o] - mu * sc;
}

// ---------------- stats pass 2: scalar sum/sumsq of gate --------------------
__global__ __launch_bounds__(256) void stats2_kernel(
    const float* __restrict__ P, const float* __restrict__ Q,
    const int* __restrict__ idx, const float* __restrict__ scale,
    const float* __restrict__ shift, const float* __restrict__ Wg,
    const float* __restrict__ bg, float* __restrict__ gstats) {
  int lane = threadIdx.x & 63;
  int wid  = threadIdx.x >> 6;
  int gw   = blockIdx.x * 4 + wid;
  const int npw = NTOT / 1024;
  int n0 = gw * npw;
  float sc = scale[lane], sh = shift[lane], wg = Wg[lane], bgv = bg[0];
  float s = 0.f, ss = 0.f;
  for (int i = n0; i < n0 + npw; ++i) {
    float qv = Q[(size_t)i*ODIM + lane];
    #pragma unroll
    for (int k = 0; k < KNN; ++k) {
      int j = idx[(size_t)i*KNN + k];
      float z = (qv + P[(size_t)j*ODIM + lane]) * sc + sh;
      float hn = z / (1.f + expf(-z));
      float v = hn * wg;
      #pragma unroll
      for (int off = 32; off > 0; off >>= 1) v += __shfl_xor(v, off);
      if (lane == 0) { float gt = v + bgv; s += gt; ss += gt*gt; }
    }
  }
  __shared__ float pw[4], pws[4];
  if (lane == 0) { pw[wid] = s; pws[wid] = ss; }
  __syncthreads();
  if (threadIdx.x == 0) {
    atomicAdd(&gstats[0], pw[0]+pw[1]+pw[2]+pw[3]);
    atomicAdd(&gstats[1], pws[0]+pws[1]+pws[2]+pws[3]);
  }
}

__global__ void fin2_kernel(const float* __restrict__ gstats,
    const float* __restrict__ gg, const float* __restrict__ beg,
    float* __restrict__ gsc) {
  float mu  = gstats[0] / (float)NEDGE;
  float var = gstats[1] / (float)NEDGE - mu*mu;
  float inv = 1.f / sqrtf(var + EPSBN);
  float s = gg[0] * inv;
  gsc[0] = s; gsc[1] = beg[0] - mu * s;
}

// ---------------- final: hn, gate, softmax over K, weighted sum -------------
__global__ __launch_bounds__(256) void final_kernel(
    const float* __restrict__ P, const float* __restrict__ Q,
    const int* __restrict__ idx, const float* __restrict__ scale,
    const float* __restrict__ shift, const float* __restrict__ Wg,
    const float* __restrict__ bg, const float* __restrict__ gsc,
    float* __restrict__ out) {
  int lane = threadIdx.x & 63;
  int wid  = threadIdx.x >> 6;
  int i = blockIdx.x * 4 + wid;
  float sc = scale[lane], sh = shift[lane], wg = Wg[lane], bgv = bg[0];
  float gscale = gsc[0], gshift = gsc[1];
  float qv = Q[(size_t)i*ODIM + lane];
  float hn[KNN], gt[KNN];
  #pragma unroll
  for (int k = 0; k < KNN; ++k) {
    int j = idx[(size_t)i*KNN + k];
    float z = (qv + P[(size_t)j*ODIM + lane]) * sc + sh;
    float h = z / (1.f + expf(-z));
    hn[k] = h;
    float v = h * wg;
    #pragma unroll
    for (int off = 32; off > 0; off >>= 1) v += __shfl_xor(v, off);
    float g = v + bgv;
    float zg = g * gscale + gshift;
    gt[k] = zg / (1.f + expf(-zg));
  }
  float m = gt[0];
  #pragma unroll
  for (int k = 1; k < KNN; ++k) m = fmaxf(m, gt[k]);
  float se = 0.f;
  #pragma unroll
  for (int k = 0; k < KNN; ++k) { gt[k] = expf(gt[k] - m); se += gt[k]; }
  float invs = 1.f / se;
  float acc = 0.f;
  #pragma unroll
  for (int k = 0; k < KNN; ++k) acc += gt[k] * invs * hn[k];
  out[(size_t)i*ODIM + lane] = acc;
}

extern "C" void kernel_launch(void* const* d_in, const int* in_sizes, int n_in,
                              void* d_out, int out_size, void* d_ws, size_t ws_size,
                              hipStream_t stream) {
  const float* x   = (const float*)d_in[0];
  // d_in[1] = batch (unused: sorted equal-size graphs)
  const float* W1  = (const float*)d_in[2];
  const float* b1  = (const float*)d_in[3];
  const float* g1  = (const float*)d_in[4];
  const float* be1 = (const float*)d_in[5];
  const float* Wg  = (const float*)d_in[6];
  const float* bg  = (const float*)d_in[7];
  const float* gg  = (const float*)d_in[8];
  const float* beg = (const float*)d_in[9];
  float* out = (float*)d_out;

  char* ws = (char*)d_ws;
  int*   idx   = (int*)  (ws);                                 // 2 MB
  float* P     = (float*)(ws + 2097152);                       // 8 MB
  float* Q     = (float*)(ws + 2097152 + 8388608);             // 8 MB
  float* sq    = (float*)(ws + 2097152 + 16777216);            // 128 KB
  float* stats = (float*)(ws + 2097152 + 16777216 + 131072);   // 128 f
  float* gstat = stats + 128;                                  // 2 f
  float* scale = gstat + 2;                                    // 64 f
  float* shift = scale + 64;                                   // 64 f
  float* gsc   = shift + 64;                                   // 2 f

  hipMemsetAsync(stats, 0, (128 + 2) * sizeof(float), stream);

  pq_kernel<<<NTOT/4, 256, 0, stream>>>(x, W1, b1, P, Q, sq);
  knn_kernel<<<NTOT/ROWS, 256, 0, stream>>>(x, sq, idx);
  stats1_kernel<<<256, 256, 0, stream>>>(P, Q, idx, stats);
  fin1_kernel<<<1, 64, 0, stream>>>(stats, g1, be1, scale, shift);
  stats2_kernel<<<256, 256, 0, stream>>>(P, Q, idx, scale, shift, Wg, bg, gstat);
  fin2_kernel<<<1, 1, 0, stream>>>(gstat, gg, beg, gsc);
  final_kernel<<<NTOT/4, 256, 0, stream>>>(P, Q, idx, scale, shift, Wg, bg, gsc, out);
}

// Round 2
// 473.229 us; speedup vs baseline: 1.8912x; 1.8912x over previous
//
#include <hip/hip_runtime.h>
#include <math.h>
#include <float.h>

#define BGRAPH 16
#define NPTS   2048
#define CDIM   16
#define ODIM   64
#define KNN    16
#define NTOT   (BGRAPH*NPTS)     // 32768
#define NEDGE  (NTOT*KNN)        // 524288
#define EPSBN  1e-5f

// ---------------- P = x@W1b, Q = x@(W1a-W1b)+b1, sq = rowsum(x*x) ----------
__global__ __launch_bounds__(256) void pq_kernel(
    const float* __restrict__ x, const float* __restrict__ W1,
    const float* __restrict__ b1,
    float* __restrict__ P, float* __restrict__ Q, float* __restrict__ sq) {
  int lane = threadIdx.x & 63;
  int nin  = threadIdx.x >> 6;           // node within block (0..3)
  int node = blockIdx.x * 4 + nin;
  __shared__ float xs[4][CDIM];
  if (threadIdx.x < 4*CDIM) {
    int n = threadIdx.x / CDIM, c = threadIdx.x % CDIM;
    xs[n][c] = x[(blockIdx.x*4 + n)*CDIM + c];
  }
  __syncthreads();
  float p = 0.f, q = b1[lane];
  #pragma unroll
  for (int c = 0; c < CDIM; ++c) {
    float xv = xs[nin][c];
    float wb = W1[(c+CDIM)*ODIM + lane];
    float wa = W1[c*ODIM + lane];
    p += xv * wb;
    q += xv * (wa - wb);
  }
  P[node*ODIM + lane] = p;
  Q[node*ODIM + lane] = q;
  if (lane == 0) {
    float s = 0.f;
    #pragma unroll
    for (int c = 0; c < CDIM; ++c) { float xv = xs[nin][c]; s += xv*xv; }
    sq[node] = s;
  }
}

// ---------------- kNN: wave-local selection, no barriers in selection -------
// block = 256 thr = 4 waves; each wave owns 2 rows; 8 rows/block; 4096 blocks.
// distances live in registers: d[2][32] per lane, candidate j = t*256+4*lane+rr
#define KROWS 8
__device__ __forceinline__ unsigned long long packkey(float dv, int j) {
  unsigned ub = __float_as_uint(dv);
  ub ^= ((unsigned)((int)ub >> 31)) | 0x80000000u;   // monotone f32->u32
  return (((unsigned long long)ub) << 32) | (unsigned)j;
}

__global__ __launch_bounds__(256) void knn_kernel(
    const float* __restrict__ x, const float* __restrict__ sq,
    int* __restrict__ idxOut) {
  __shared__ float sT16[CDIM][256];                 // transposed tile, 16 KB
  __shared__ unsigned long long skey[4][64];        // per-wave survivor keys
  __shared__ int scnt[4];
  const int tid  = threadIdx.x;
  const int lane = tid & 63;
  const int w    = tid >> 6;
  const int blocksPerGraph = NPTS / KROWS;          // 256
  const int g     = blockIdx.x / blocksPerGraph;
  const int rb    = (blockIdx.x % blocksPerGraph) * KROWS;
  const int gbase = g * NPTS;
  const int r0    = rb + w*2;                       // this wave's rows: r0, r0+1

  // target rows -> registers (wave-uniform values)
  float tg[2][CDIM]; float tsq[2];
  #pragma unroll
  for (int rp = 0; rp < 2; ++rp) {
    const float4* tp = (const float4*)(x + (size_t)(gbase + r0 + rp)*CDIM);
    float4 t0 = tp[0], t1 = tp[1], t2 = tp[2], t3 = tp[3];
    tg[rp][0]=t0.x; tg[rp][1]=t0.y; tg[rp][2]=t0.z; tg[rp][3]=t0.w;
    tg[rp][4]=t1.x; tg[rp][5]=t1.y; tg[rp][6]=t1.z; tg[rp][7]=t1.w;
    tg[rp][8]=t2.x; tg[rp][9]=t2.y; tg[rp][10]=t2.z; tg[rp][11]=t2.w;
    tg[rp][12]=t3.x; tg[rp][13]=t3.y; tg[rp][14]=t3.z; tg[rp][15]=t3.w;
    tsq[rp] = sq[gbase + r0 + rp];
  }

  float d[2][32];

  for (int t = 0; t < NPTS/256; ++t) {
    __syncthreads();
    // cooperative transposed tile load: 256 threads x 16 floats
    const float4* xp = (const float4*)(x + (size_t)(gbase + t*256 + tid)*CDIM);
    float4 a0 = xp[0], a1 = xp[1], a2 = xp[2], a3 = xp[3];
    sT16[0][tid]=a0.x;  sT16[1][tid]=a0.y;  sT16[2][tid]=a0.z;  sT16[3][tid]=a0.w;
    sT16[4][tid]=a1.x;  sT16[5][tid]=a1.y;  sT16[6][tid]=a1.z;  sT16[7][tid]=a1.w;
    sT16[8][tid]=a2.x;  sT16[9][tid]=a2.y;  sT16[10][tid]=a2.z; sT16[11][tid]=a2.w;
    sT16[12][tid]=a3.x; sT16[13][tid]=a3.y; sT16[14][tid]=a3.z; sT16[15][tid]=a3.w;
    __syncthreads();

    float4 sq4 = *(const float4*)(sq + gbase + t*256 + 4*lane);
    float sqv[4] = {sq4.x, sq4.y, sq4.z, sq4.w};

    float dot[2][4] = {{0.f,0.f,0.f,0.f},{0.f,0.f,0.f,0.f}};
    #pragma unroll
    for (int c = 0; c < CDIM; ++c) {
      float4 cv = *(const float4*)(&sT16[c][4*lane]);   // one clean ds_read_b128
      float cvv[4]; cvv[0]=cv.x; cvv[1]=cv.y; cvv[2]=cv.z; cvv[3]=cv.w;
      #pragma unroll
      for (int rp = 0; rp < 2; ++rp)
        #pragma unroll
        for (int rr = 0; rr < 4; ++rr)
          dot[rp][rr] += tg[rp][c] * cvv[rr];
    }
    #pragma unroll
    for (int rp = 0; rp < 2; ++rp)
      #pragma unroll
      for (int rr = 0; rr < 4; ++rr)
        d[rp][t*4 + rr] = tsq[rp] + sqv[rr] - 2.f*dot[rp][rr];
  }

  // ---------------- wave-local selection per row ----------------
  #pragma unroll 1
  for (int rp = 0; rp < 2; ++rp) {
    // 1) per-lane min (value only)
    float lmin = d[rp][0];
    #pragma unroll
    for (int s = 1; s < 32; ++s) lmin = fminf(lmin, d[rp][s]);

    // 2) bitonic sort the 64 lane-minima (f32, ascending) -> T = lane 15
    float v = lmin;
    #pragma unroll
    for (int k = 2; k <= 64; k <<= 1) {
      #pragma unroll
      for (int j = k >> 1; j > 0; j >>= 1) {
        float o = __shfl_xor(v, j);
        bool asc   = ((lane & k) == 0);
        bool lower = ((lane & j) == 0);
        float mn = fminf(v, o), mx = fmaxf(v, o);
        v = (asc == lower) ? mn : mx;
      }
    }
    float T = __shfl(v, 15);   // valid upper bound on the 16th-smallest

    // 3) filter + compact survivors into per-wave LDS
    if (lane == 0) scnt[w] = 0;
    #pragma unroll
    for (int s = 0; s < 32; ++s) {
      if (d[rp][s] <= T) {
        int p = atomicAdd(&scnt[w], 1);
        if (p < 64) {
          int j = (s >> 2)*256 + 4*lane + (s & 3);
          skey[w][p] = packkey(d[rp][s], j);
        }
      }
    }
    int M = scnt[w];
    int row = gbase + r0 + rp;

    if (M <= 64) {
      // 4) one u64 bitonic sort across lanes; lanes 0..15 hold the top-16
      unsigned long long key = (lane < M) ? skey[w][lane] : ~0ull;
      #pragma unroll
      for (int k = 2; k <= 64; k <<= 1) {
        #pragma unroll
        for (int j = k >> 1; j > 0; j >>= 1) {
          unsigned long long o = __shfl_xor(key, j);
          bool asc   = ((lane & k) == 0);
          bool lower = ((lane & j) == 0);
          unsigned long long mn = (key < o) ? key : o;
          unsigned long long mx = (key < o) ? o : key;
          key = (asc == lower) ? mn : mx;
        }
      }
      if (lane < KNN)
        idxOut[(size_t)row*KNN + lane] = gbase + (int)(key & 0xffffffffu);
    } else {
      // exact fallback (astronomically rare): 16 iterative argmin rounds
      for (int sel = 0; sel < KNN; ++sel) {
        unsigned long long lb = ~0ull;
        #pragma unroll
        for (int s = 0; s < 32; ++s) {
          int j = (s >> 2)*256 + 4*lane + (s & 3);
          unsigned long long ks = packkey(d[rp][s], j);
          if (ks < lb) lb = ks;
        }
        #pragma unroll
        for (int off = 32; off > 0; off >>= 1) {
          unsigned long long o = __shfl_xor(lb, off);
          if (o < lb) lb = o;
        }
        if (lane == 0)
          idxOut[(size_t)row*KNN + sel] = gbase + (int)(lb & 0xffffffffu);
        #pragma unroll
        for (int s = 0; s < 32; ++s) {
          int j = (s >> 2)*256 + 4*lane + (s & 3);
          if (packkey(d[rp][s], j) == lb) d[rp][s] = FLT_MAX;
        }
      }
    }
  }
}

// ---------------- stats pass 1: per-channel sum/sumsq of h ------------------
__global__ __launch_bounds__(256) void stats1_kernel(
    const float* __restrict__ P, const float* __restrict__ Q,
    const int* __restrict__ idx, float* __restrict__ stats) {
  int lane = threadIdx.x & 63;
  int wid  = threadIdx.x >> 6;
  int gw   = blockIdx.x * 4 + wid;           // 0..1023
  const int npw = NTOT / 1024;               // 32 nodes per wave
  int n0 = gw * npw;
  float s = 0.f, ss = 0.f;
  for (int i = n0; i < n0 + npw; ++i) {
    float qv = Q[(size_t)i*ODIM + lane];
    #pragma unroll
    for (int k = 0; k < KNN; ++k) {
      int j = idx[(size_t)i*KNN + k];
      float h = qv + P[(size_t)j*ODIM + lane];
      s += h; ss += h*h;
    }
  }
  __shared__ float ls[ODIM], lss[ODIM];
  if (threadIdx.x < ODIM) { ls[threadIdx.x] = 0.f; lss[threadIdx.x] = 0.f; }
  __syncthreads();
  atomicAdd(&ls[lane], s);
  atomicAdd(&lss[lane], ss);
  __syncthreads();
  if (threadIdx.x < ODIM)        atomicAdd(&stats[threadIdx.x], ls[threadIdx.x]);
  else if (threadIdx.x < 2*ODIM) atomicAdd(&stats[threadIdx.x], lss[threadIdx.x - ODIM]);
}

__global__ void fin1_kernel(const float* __restrict__ stats,
    const float* __restrict__ g1, const float* __restrict__ be1,
    float* __restrict__ scale, float* __restrict__ shift) {
  int o = threadIdx.x;
  float mu  = stats[o] / (float)NEDGE;
  float var = stats[64+o] / (float)NEDGE - mu*mu;
  float inv = 1.0f / sqrtf(var + EPSBN);
  float sc = g1[o] * inv;
  scale[o] = sc;
  shift[o] = be1[o] - mu * sc;
}

// ---------------- stats pass 2: scalar sum/sumsq of gate --------------------
__global__ __launch_bounds__(256) void stats2_kernel(
    const float* __restrict__ P, const float* __restrict__ Q,
    const int* __restrict__ idx, const float* __restrict__ scale,
    const float* __restrict__ shift, const float* __restrict__ Wg,
    const float* __restrict__ bg, float* __restrict__ gstats) {
  int lane = threadIdx.x & 63;
  int wid  = threadIdx.x >> 6;
  int gw   = blockIdx.x * 4 + wid;
  const int npw = NTOT / 1024;
  int n0 = gw * npw;
  float sc = scale[lane], sh = shift[lane], wg = Wg[lane], bgv = bg[0];
  float s = 0.f, ss = 0.f;
  for (int i = n0; i < n0 + npw; ++i) {
    float qv = Q[(size_t)i*ODIM + lane];
    #pragma unroll
    for (int k = 0; k < KNN; ++k) {
      int j = idx[(size_t)i*KNN + k];
      float z = (qv + P[(size_t)j*ODIM + lane]) * sc + sh;
      float hn = z / (1.f + expf(-z));
      float v = hn * wg;
      #pragma unroll
      for (int off = 32; off > 0; off >>= 1) v += __shfl_xor(v, off);
      if (lane == 0) { float gt = v + bgv; s += gt; ss += gt*gt; }
    }
  }
  __shared__ float pw[4], pws[4];
  if (lane == 0) { pw[wid] = s; pws[wid] = ss; }
  __syncthreads();
  if (threadIdx.x == 0) {
    atomicAdd(&gstats[0], pw[0]+pw[1]+pw[2]+pw[3]);
    atomicAdd(&gstats[1], pws[0]+pws[1]+pws[2]+pws[3]);
  }
}

__global__ void fin2_kernel(const float* __restrict__ gstats,
    const float* __restrict__ gg, const float* __restrict__ beg,
    float* __restrict__ gsc) {
  float mu  = gstats[0] / (float)NEDGE;
  float var = gstats[1] / (float)NEDGE - mu*mu;
  float inv = 1.f / sqrtf(var + EPSBN);
  float s = gg[0] * inv;
  gsc[0] = s; gsc[1] = beg[0] - mu * s;
}

// ---------------- final: hn, gate, softmax over K, weighted sum -------------
__global__ __launch_bounds__(256) void final_kernel(
    const float* __restrict__ P, const float* __restrict__ Q,
    const int* __restrict__ idx, const float* __restrict__ scale,
    const float* __restrict__ shift, const float* __restrict__ Wg,
    const float* __restrict__ bg, const float* __restrict__ gsc,
    float* __restrict__ out) {
  int lane = threadIdx.x & 63;
  int wid  = threadIdx.x >> 6;
  int i = blockIdx.x * 4 + wid;
  float sc = scale[lane], sh = shift[lane], wg = Wg[lane], bgv = bg[0];
  float gscale = gsc[0], gshift = gsc[1];
  float qv = Q[(size_t)i*ODIM + lane];
  float hn[KNN], gt[KNN];
  #pragma unroll
  for (int k = 0; k < KNN; ++k) {
    int j = idx[(size_t)i*KNN + k];
    float z = (qv + P[(size_t)j*ODIM + lane]) * sc + sh;
    float h = z / (1.f + expf(-z));
    hn[k] = h;
    float v = h * wg;
    #pragma unroll
    for (int off = 32; off > 0; off >>= 1) v += __shfl_xor(v, off);
    float g = v + bgv;
    float zg = g * gscale + gshift;
    gt[k] = zg / (1.f + expf(-zg));
  }
  float m = gt[0];
  #pragma unroll
  for (int k = 1; k < KNN; ++k) m = fmaxf(m, gt[k]);
  float se = 0.f;
  #pragma unroll
  for (int k = 0; k < KNN; ++k) { gt[k] = expf(gt[k] - m); se += gt[k]; }
  float invs = 1.f / se;
  float acc = 0.f;
  #pragma unroll
  for (int k = 0; k < KNN; ++k) acc += gt[k] * invs * hn[k];
  out[(size_t)i*ODIM + lane] = acc;
}

extern "C" void kernel_launch(void* const* d_in, const int* in_sizes, int n_in,
                              void* d_out, int out_size, void* d_ws, size_t ws_size,
                              hipStream_t stream) {
  const float* x   = (const float*)d_in[0];
  // d_in[1] = batch (unused: sorted equal-size graphs)
  const float* W1  = (const float*)d_in[2];
  const float* b1  = (const float*)d_in[3];
  const float* g1  = (const float*)d_in[4];
  const float* be1 = (const float*)d_in[5];
  const float* Wg  = (const float*)d_in[6];
  const float* bg  = (const float*)d_in[7];
  const float* gg  = (const float*)d_in[8];
  const float* beg = (const float*)d_in[9];
  float* out = (float*)d_out;

  char* ws = (char*)d_ws;
  int*   idx   = (int*)  (ws);                                 // 2 MB
  float* P     = (float*)(ws + 2097152);                       // 8 MB
  float* Q     = (float*)(ws + 2097152 + 8388608);             // 8 MB
  float* sq    = (float*)(ws + 2097152 + 16777216);            // 128 KB
  float* stats = (float*)(ws + 2097152 + 16777216 + 131072);   // 128 f
  float* gstat = stats + 128;                                  // 2 f
  float* scale = gstat + 2;                                    // 64 f
  float* shift = scale + 64;                                   // 64 f
  float* gsc   = shift + 64;                                   // 2 f

  hipMemsetAsync(stats, 0, (128 + 2) * sizeof(float), stream);

  pq_kernel<<<NTOT/4, 256, 0, stream>>>(x, W1, b1, P, Q, sq);
  knn_kernel<<<NTOT/KROWS, 256, 0, stream>>>(x, sq, idx);
  stats1_kernel<<<256, 256, 0, stream>>>(P, Q, idx, stats);
  fin1_kernel<<<1, 64, 0, stream>>>(stats, g1, be1, scale, shift);
  stats2_kernel<<<256, 256, 0, stream>>>(P, Q, idx, scale, shift, Wg, bg, gstat);
  fin2_kernel<<<1, 1, 0, stream>>>(gstat, gg, beg, gsc);
  final_kernel<<<NTOT/4, 256, 0, stream>>>(P, Q, idx, scale, shift, Wg, bg, gsc, out);
}

// Round 3
// 352.767 us; speedup vs baseline: 2.5370x; 1.3415x over previous
//
#include <hip/hip_runtime.h>
#include <math.h>
#include <float.h>

#define BGRAPH 16
#define NPTS   2048
#define CDIM   16
#define ODIM   64
#define KNN    16
#define NTOT   (BGRAPH*NPTS)     // 32768
#define NEDGE  (NTOT*KNN)        // 524288
#define EPSBN  1e-5f
#define NBLK_E 2048              // blocks for edge-stat passes
#define NPW    4                 // nodes per wave in edge-stat passes

// ---------------- P = x@W1b, Q = x@(W1a-W1b)+b1, sq = rowsum(x*x) ----------
__global__ __launch_bounds__(256) void pq_kernel(
    const float* __restrict__ x, const float* __restrict__ W1,
    const float* __restrict__ b1,
    float* __restrict__ P, float* __restrict__ Q, float* __restrict__ sq) {
  int lane = threadIdx.x & 63;
  int nin  = threadIdx.x >> 6;           // node within block (0..3)
  int node = blockIdx.x * 4 + nin;
  __shared__ float xs[4][CDIM];
  if (threadIdx.x < 4*CDIM) {
    int n = threadIdx.x / CDIM, c = threadIdx.x % CDIM;
    xs[n][c] = x[(blockIdx.x*4 + n)*CDIM + c];
  }
  __syncthreads();
  float p = 0.f, q = b1[lane];
  #pragma unroll
  for (int c = 0; c < CDIM; ++c) {
    float xv = xs[nin][c];
    float wb = W1[(c+CDIM)*ODIM + lane];
    float wa = W1[c*ODIM + lane];
    p += xv * wb;
    q += xv * (wa - wb);
  }
  P[node*ODIM + lane] = p;
  Q[node*ODIM + lane] = q;
  if (lane == 0) {
    float s = 0.f;
    #pragma unroll
    for (int c = 0; c < CDIM; ++c) { float xv = xs[nin][c]; s += xv*xv; }
    sq[node] = s;
  }
}

// ---------------- kNN: wave-local selection, no barriers in selection -------
#define KROWS 8
__device__ __forceinline__ unsigned long long packkey(float dv, int j) {
  unsigned ub = __float_as_uint(dv);
  ub ^= ((unsigned)((int)ub >> 31)) | 0x80000000u;   // monotone f32->u32
  return (((unsigned long long)ub) << 32) | (unsigned)j;
}

__global__ __launch_bounds__(256) void knn_kernel(
    const float* __restrict__ x, const float* __restrict__ sq,
    int* __restrict__ idxOut) {
  __shared__ float sT16[CDIM][256];                 // transposed tile, 16 KB
  __shared__ unsigned long long skey[4][64];        // per-wave survivor keys
  __shared__ int scnt[4];
  const int tid  = threadIdx.x;
  const int lane = tid & 63;
  const int w    = tid >> 6;
  const int blocksPerGraph = NPTS / KROWS;          // 256
  const int g     = blockIdx.x / blocksPerGraph;
  const int rb    = (blockIdx.x % blocksPerGraph) * KROWS;
  const int gbase = g * NPTS;
  const int r0    = rb + w*2;                       // this wave's rows: r0, r0+1

  float tg[2][CDIM]; float tsq[2];
  #pragma unroll
  for (int rp = 0; rp < 2; ++rp) {
    const float4* tp = (const float4*)(x + (size_t)(gbase + r0 + rp)*CDIM);
    float4 t0 = tp[0], t1 = tp[1], t2 = tp[2], t3 = tp[3];
    tg[rp][0]=t0.x; tg[rp][1]=t0.y; tg[rp][2]=t0.z; tg[rp][3]=t0.w;
    tg[rp][4]=t1.x; tg[rp][5]=t1.y; tg[rp][6]=t1.z; tg[rp][7]=t1.w;
    tg[rp][8]=t2.x; tg[rp][9]=t2.y; tg[rp][10]=t2.z; tg[rp][11]=t2.w;
    tg[rp][12]=t3.x; tg[rp][13]=t3.y; tg[rp][14]=t3.z; tg[rp][15]=t3.w;
    tsq[rp] = sq[gbase + r0 + rp];
  }

  float d[2][32];

  for (int t = 0; t < NPTS/256; ++t) {
    __syncthreads();
    const float4* xp = (const float4*)(x + (size_t)(gbase + t*256 + tid)*CDIM);
    float4 a0 = xp[0], a1 = xp[1], a2 = xp[2], a3 = xp[3];
    sT16[0][tid]=a0.x;  sT16[1][tid]=a0.y;  sT16[2][tid]=a0.z;  sT16[3][tid]=a0.w;
    sT16[4][tid]=a1.x;  sT16[5][tid]=a1.y;  sT16[6][tid]=a1.z;  sT16[7][tid]=a1.w;
    sT16[8][tid]=a2.x;  sT16[9][tid]=a2.y;  sT16[10][tid]=a2.z; sT16[11][tid]=a2.w;
    sT16[12][tid]=a3.x; sT16[13][tid]=a3.y; sT16[14][tid]=a3.z; sT16[15][tid]=a3.w;
    __syncthreads();

    float4 sq4 = *(const float4*)(sq + gbase + t*256 + 4*lane);
    float sqv[4] = {sq4.x, sq4.y, sq4.z, sq4.w};

    float dot[2][4] = {{0.f,0.f,0.f,0.f},{0.f,0.f,0.f,0.f}};
    #pragma unroll
    for (int c = 0; c < CDIM; ++c) {
      float4 cv = *(const float4*)(&sT16[c][4*lane]);
      float cvv[4]; cvv[0]=cv.x; cvv[1]=cv.y; cvv[2]=cv.z; cvv[3]=cv.w;
      #pragma unroll
      for (int rp = 0; rp < 2; ++rp)
        #pragma unroll
        for (int rr = 0; rr < 4; ++rr)
          dot[rp][rr] += tg[rp][c] * cvv[rr];
    }
    #pragma unroll
    for (int rp = 0; rp < 2; ++rp)
      #pragma unroll
      for (int rr = 0; rr < 4; ++rr)
        d[rp][t*4 + rr] = tsq[rp] + sqv[rr] - 2.f*dot[rp][rr];
  }

  #pragma unroll 1
  for (int rp = 0; rp < 2; ++rp) {
    float lmin = d[rp][0];
    #pragma unroll
    for (int s = 1; s < 32; ++s) lmin = fminf(lmin, d[rp][s]);

    float v = lmin;
    #pragma unroll
    for (int k = 2; k <= 64; k <<= 1) {
      #pragma unroll
      for (int j = k >> 1; j > 0; j >>= 1) {
        float o = __shfl_xor(v, j);
        bool asc   = ((lane & k) == 0);
        bool lower = ((lane & j) == 0);
        float mn = fminf(v, o), mx = fmaxf(v, o);
        v = (asc == lower) ? mn : mx;
      }
    }
    float T = __shfl(v, 15);

    if (lane == 0) scnt[w] = 0;
    #pragma unroll
    for (int s = 0; s < 32; ++s) {
      if (d[rp][s] <= T) {
        int p = atomicAdd(&scnt[w], 1);
        if (p < 64) {
          int j = (s >> 2)*256 + 4*lane + (s & 3);
          skey[w][p] = packkey(d[rp][s], j);
        }
      }
    }
    int M = scnt[w];
    int row = gbase + r0 + rp;

    if (M <= 64) {
      unsigned long long key = (lane < M) ? skey[w][lane] : ~0ull;
      #pragma unroll
      for (int k = 2; k <= 64; k <<= 1) {
        #pragma unroll
        for (int j = k >> 1; j > 0; j >>= 1) {
          unsigned long long o = __shfl_xor(key, j);
          bool asc   = ((lane & k) == 0);
          bool lower = ((lane & j) == 0);
          unsigned long long mn = (key < o) ? key : o;
          unsigned long long mx = (key < o) ? o : key;
          key = (asc == lower) ? mn : mx;
        }
      }
      if (lane < KNN)
        idxOut[(size_t)row*KNN + lane] = gbase + (int)(key & 0xffffffffu);
    } else {
      for (int sel = 0; sel < KNN; ++sel) {
        unsigned long long lb = ~0ull;
        #pragma unroll
        for (int s = 0; s < 32; ++s) {
          int j = (s >> 2)*256 + 4*lane + (s & 3);
          unsigned long long ks = packkey(d[rp][s], j);
          if (ks < lb) lb = ks;
        }
        #pragma unroll
        for (int off = 32; off > 0; off >>= 1) {
          unsigned long long o = __shfl_xor(lb, off);
          if (o < lb) lb = o;
        }
        if (lane == 0)
          idxOut[(size_t)row*KNN + sel] = gbase + (int)(lb & 0xffffffffu);
        #pragma unroll
        for (int s = 0; s < 32; ++s) {
          int j = (s >> 2)*256 + 4*lane + (s & 3);
          if (packkey(d[rp][s], j) == lb) d[rp][s] = FLT_MAX;
        }
      }
    }
  }
}

// ---------------- stats pass 1: per-channel sum/sumsq of h ------------------
// 2048 blocks x 4 waves; 4 nodes/wave; partials -> pbuf[chanstat][block]
__global__ __launch_bounds__(256) void stats1_kernel(
    const float* __restrict__ P, const float* __restrict__ Q,
    const int* __restrict__ idx, float* __restrict__ pbuf) {
  int lane = threadIdx.x & 63;
  int wid  = threadIdx.x >> 6;
  int gw   = blockIdx.x * 4 + wid;
  int n0 = gw * NPW;
  float s = 0.f, ss = 0.f;
  #pragma unroll
  for (int ii = 0; ii < NPW; ++ii) {
    int i = n0 + ii;
    float qv = Q[(size_t)i*ODIM + lane];
    #pragma unroll
    for (int k = 0; k < KNN; ++k) {
      int j = idx[(size_t)i*KNN + k];
      float h = qv + P[(size_t)j*ODIM + lane];
      s += h; ss += h*h;
    }
  }
  __shared__ float ls[4][ODIM], lss[4][ODIM];
  ls[wid][lane] = s; lss[wid][lane] = ss;
  __syncthreads();
  int tid = threadIdx.x;
  if (tid < ODIM) {
    float a = ls[0][tid] + ls[1][tid] + ls[2][tid] + ls[3][tid];
    pbuf[(size_t)tid*NBLK_E + blockIdx.x] = a;
  } else if (tid < 2*ODIM) {
    int o = tid - ODIM;
    float a = lss[0][o] + lss[1][o] + lss[2][o] + lss[3][o];
    pbuf[(size_t)(ODIM+o)*NBLK_E + blockIdx.x] = a;
  }
}

// 64 blocks x 1 wave: block o reduces channel o's sum & sumsq rows of pbuf
__global__ __launch_bounds__(64) void fin1_kernel(
    const float* __restrict__ pbuf,
    const float* __restrict__ g1, const float* __restrict__ be1,
    float* __restrict__ scale, float* __restrict__ shift) {
  int o = blockIdx.x, lane = threadIdx.x;
  const float* ps = pbuf + (size_t)o*NBLK_E;
  const float* pq = pbuf + (size_t)(ODIM+o)*NBLK_E;
  float s = 0.f, ss = 0.f;
  for (int t = lane; t < NBLK_E; t += 64) { s += ps[t]; ss += pq[t]; }
  #pragma unroll
  for (int off = 32; off > 0; off >>= 1) {
    s  += __shfl_xor(s, off);
    ss += __shfl_xor(ss, off);
  }
  if (lane == 0) {
    float mu  = s / (float)NEDGE;
    float var = ss / (float)NEDGE - mu*mu;
    float inv = 1.0f / sqrtf(var + EPSBN);
    float sc = g1[o] * inv;
    scale[o] = sc;
    shift[o] = be1[o] - mu * sc;
  }
}

// ---------------- stats pass 2: gate values + scalar sum/sumsq --------------
__global__ __launch_bounds__(256) void stats2_kernel(
    const float* __restrict__ P, const float* __restrict__ Q,
    const int* __restrict__ idx, const float* __restrict__ scale,
    const float* __restrict__ shift, const float* __restrict__ Wg,
    const float* __restrict__ bg, float* __restrict__ gtbuf,
    float* __restrict__ gpart) {
  int lane = threadIdx.x & 63;
  int wid  = threadIdx.x >> 6;
  int gw   = blockIdx.x * 4 + wid;
  int n0 = gw * NPW;
  float sc = scale[lane], sh = shift[lane], wg = Wg[lane], bgv = bg[0];
  float s = 0.f, ss = 0.f;
  #pragma unroll
  for (int ii = 0; ii < NPW; ++ii) {
    int i = n0 + ii;
    float qv = Q[(size_t)i*ODIM + lane];
    #pragma unroll
    for (int k = 0; k < KNN; ++k) {
      int j = idx[(size_t)i*KNN + k];
      float z = (qv + P[(size_t)j*ODIM + lane]) * sc + sh;
      float hn = z / (1.f + expf(-z));
      float v = hn * wg;
      #pragma unroll
      for (int off = 32; off > 0; off >>= 1) v += __shfl_xor(v, off);
      float g = v + bgv;               // full sum on all lanes after butterfly
      if (lane == 0) {
        gtbuf[(size_t)i*KNN + k] = g;
        s += g; ss += g*g;
      }
    }
  }
  __shared__ float pw[4], pws[4];
  if (lane == 0) { pw[wid] = s; pws[wid] = ss; }
  __syncthreads();
  if (threadIdx.x == 0) {
    gpart[2*blockIdx.x]   = pw[0]+pw[1]+pw[2]+pw[3];
    gpart[2*blockIdx.x+1] = pws[0]+pws[1]+pws[2]+pws[3];
  }
}

// 1 block x 256: reduce 2048 (s,ss) pairs -> gate BN scale/shift
__global__ __launch_bounds__(256) void fin2_kernel(
    const float* __restrict__ gpart,
    const float* __restrict__ gg, const float* __restrict__ beg,
    float* __restrict__ gsc) {
  int tid = threadIdx.x;
  float s = 0.f, ss = 0.f;
  for (int t = tid; t < NBLK_E; t += 256) { s += gpart[2*t]; ss += gpart[2*t+1]; }
  __shared__ float as[256], bs[256];
  as[tid] = s; bs[tid] = ss;
  __syncthreads();
  #pragma unroll
  for (int st = 128; st > 0; st >>= 1) {
    if (tid < st) { as[tid] += as[tid+st]; bs[tid] += bs[tid+st]; }
    __syncthreads();
  }
  if (tid == 0) {
    float mu  = as[0] / (float)NEDGE;
    float var = bs[0] / (float)NEDGE - mu*mu;
    float inv = 1.f / sqrtf(var + EPSBN);
    float sg = gg[0] * inv;
    gsc[0] = sg; gsc[1] = beg[0] - mu * sg;
  }
}

// ---------------- final: hn, gate from gtbuf, softmax over K, weighted sum --
__global__ __launch_bounds__(256) void final_kernel(
    const float* __restrict__ P, const float* __restrict__ Q,
    const int* __restrict__ idx, const float* __restrict__ scale,
    const float* __restrict__ shift, const float* __restrict__ gtbuf,
    const float* __restrict__ gsc, float* __restrict__ out) {
  int lane = threadIdx.x & 63;
  int wid  = threadIdx.x >> 6;
  int i = blockIdx.x * 4 + wid;
  float sc = scale[lane], sh = shift[lane];
  float gscale = gsc[0], gshift = gsc[1];
  float qv = Q[(size_t)i*ODIM + lane];
  float hn[KNN], gt[KNN];
  #pragma unroll
  for (int k = 0; k < KNN; ++k) {
    int j = idx[(size_t)i*KNN + k];
    float z = (qv + P[(size_t)j*ODIM + lane]) * sc + sh;
    hn[k] = z / (1.f + expf(-z));
    float g = gtbuf[(size_t)i*KNN + k];
    float zg = g * gscale + gshift;
    gt[k] = zg / (1.f + expf(-zg));
  }
  float m = gt[0];
  #pragma unroll
  for (int k = 1; k < KNN; ++k) m = fmaxf(m, gt[k]);
  float se = 0.f;
  #pragma unroll
  for (int k = 0; k < KNN; ++k) { gt[k] = expf(gt[k] - m); se += gt[k]; }
  float invs = 1.f / se;
  float acc = 0.f;
  #pragma unroll
  for (int k = 0; k < KNN; ++k) acc += gt[k] * invs * hn[k];
  out[(size_t)i*ODIM + lane] = acc;
}

extern "C" void kernel_launch(void* const* d_in, const int* in_sizes, int n_in,
                              void* d_out, int out_size, void* d_ws, size_t ws_size,
                              hipStream_t stream) {
  const float* x   = (const float*)d_in[0];
  // d_in[1] = batch (unused: sorted equal-size graphs)
  const float* W1  = (const float*)d_in[2];
  const float* b1  = (const float*)d_in[3];
  const float* g1  = (const float*)d_in[4];
  const float* be1 = (const float*)d_in[5];
  const float* Wg  = (const float*)d_in[6];
  const float* bg  = (const float*)d_in[7];
  const float* gg  = (const float*)d_in[8];
  const float* beg = (const float*)d_in[9];
  float* out = (float*)d_out;

  char* ws = (char*)d_ws;
  int*   idx   = (int*)  (ws);                         // 2 MB
  float* P     = (float*)(ws + 2097152);               // 8 MB
  float* Q     = (float*)(ws + 10485760);              // 8 MB
  float* sq    = (float*)(ws + 18874368);              // 128 KB
  float* pbuf  = (float*)(ws + 19005440);              // 1 MB   [128][2048]
  float* gpart = (float*)(ws + 20054016);              // 16 KB  [2048][2]
  float* gtbuf = (float*)(ws + 20070400);              // 2 MB   [NEDGE]
  float* scale = (float*)(ws + 22167552);              // 64 f
  float* shift = (float*)(ws + 22167808);              // 64 f
  float* gsc   = (float*)(ws + 22168064);              // 2 f

  pq_kernel<<<NTOT/4, 256, 0, stream>>>(x, W1, b1, P, Q, sq);
  knn_kernel<<<NTOT/KROWS, 256, 0, stream>>>(x, sq, idx);
  stats1_kernel<<<NBLK_E, 256, 0, stream>>>(P, Q, idx, pbuf);
  fin1_kernel<<<ODIM, 64, 0, stream>>>(pbuf, g1, be1, scale, shift);
  stats2_kernel<<<NBLK_E, 256, 0, stream>>>(P, Q, idx, scale, shift, Wg, bg, gtbuf, gpart);
  fin2_kernel<<<1, 256, 0, stream>>>(gpart, gg, beg, gsc);
  final_kernel<<<NTOT/4, 256, 0, stream>>>(P, Q, idx, scale, shift, gtbuf, gsc, out);
}